// Round 20
// baseline (206.652 us; speedup 1.0000x reference)
//
#include <hip/hip_runtime.h>
#include <hip/hip_bf16.h>
#include <math.h>

typedef __attribute__((ext_vector_type(8))) short short8;
typedef __attribute__((ext_vector_type(4))) short short4v;
typedef __attribute__((ext_vector_type(4))) float f32x4;
typedef unsigned short u16;

#define SC2 0.18033688011112042f   // 0.125 * log2(e)
#define L2E 1.4426950408889634f

__device__ __forceinline__ u16 f2bf(float f) {
  union { float f; unsigned u; } v; v.f = f;
  unsigned u = v.u + 0x7fffu + ((v.u >> 16) & 1u);
  return (u16)(u >> 16);
}
__device__ __forceinline__ float bf2f(u16 h) {
  union { unsigned u; float f; } v; v.u = ((unsigned)h) << 16;
  return v.f;
}
__device__ __forceinline__ float fexp2(float x) {
  float r; asm("v_exp_f32 %0, %1" : "=v"(r) : "v"(x)); return r;
}
__device__ __forceinline__ void gl_lds16(const u16* g, u16* l) {
  __builtin_amdgcn_global_load_lds(
      (const __attribute__((address_space(1))) void*)g,
      (__attribute__((address_space(3))) void*)l, 16, 0, 0);
}

// K fragment layout (3 k-subtiles): (b,h,j,d) -> ((((bh)*64 + j/16)*3 + d/32)*64 + ((d>>3)&3)*16 + (j&15))*8 + (d&7)
__device__ __forceinline__ size_t KFoff(int b, int h, int j, int d) {
  return ((((size_t)(b * 16 + h) * 64 + (j >> 4)) * 3 + (d >> 5)) * 64
          + ((d >> 3) & 3) * 16 + (j & 15)) * 8 + (d & 7);
}
// V fragment layout: (b,h,j,d) -> ((((bh)*4 + d/16)*32 + j/32)*64 + ((j>>3)&3)*16 + (d&15))*8 + (j&7)
__device__ __forceinline__ size_t VFoff(int b, int h, int j, int d) {
  return ((((size_t)(b * 16 + h) * 4 + (d >> 4)) * 32 + (j >> 5)) * 64
          + ((j >> 3) & 3) * 16 + (d & 15)) * 8 + (j & 7);
}

// ---------------- convert f32 -> bf16 (and blocks >= 8704: kaug fill) ----------------
__global__ __launch_bounds__(256) void cvt_all(
    const float* __restrict__ q, const float* __restrict__ k, const float* __restrict__ v,
    const float* __restrict__ w0, const float* __restrict__ w1, const float* __restrict__ w2,
    const float* __restrict__ w3, const float* __restrict__ w4,
    u16* __restrict__ qb, u16* __restrict__ kb, u16* __restrict__ vb,
    u16* __restrict__ w0b, u16* __restrict__ w1b, u16* __restrict__ w2b,
    u16* __restrict__ w3b, u16* __restrict__ w4b,
    const int* __restrict__ mask, u16* __restrict__ Kf) {
  int bid = blockIdx.x;
  if (bid >= 8704) {
    int bidx = bid - 8704;
    int b = bidx >> 6, jt = bidx & 63;
    int t = threadIdx.x;
    int h = t >> 4, jj = t & 15;
    int j = jt * 16 + jj;
    float jc = (float)(j - 512);
    float mbv = (mask[b * 1024 + j] == 0) ? -1.4e15f : 0.0f;
    u16* base = Kf + ((size_t)((b * 16 + h) * 64 + jt) * 3 + 2) * 512;
    short8 z8 = (short8){0, 0, 0, 0, 0, 0, 0, 0};
    short8 f8 = z8;
    f8[0] = (short)f2bf(jc * jc);
    f8[1] = (short)f2bf(jc);
    f8[2] = (short)f2bf(1.0f);
    f8[3] = (short)f2bf(mbv);
    *(short8*)(base + jj * 8) = f8;
    *(short8*)(base + 128 + jj * 8) = z8;
    *(short8*)(base + 256 + jj * 8) = z8;
    *(short8*)(base + 384 + jj * 8) = z8;
    return;
  }
  const float* s; u16* d; int base;
  if (bid < 2048)      { s = q; d = qb; base = bid; }
  else if (bid < 4096) { s = k; d = kb; base = bid - 2048; }
  else if (bid < 6144) { s = v; d = vb; base = bid - 4096; }
  else {
    int t2 = bid - 6144; int wi = t2 >> 9; base = t2 & 511;
    if (wi == 0)      { s = w0; d = w0b; }
    else if (wi == 1) { s = w1; d = w1b; }
    else if (wi == 2) { s = w2; d = w2b; }
    else if (wi == 3) { s = w3; d = w3b; }
    else              { s = w4; d = w4b; }
  }
  size_t idx = (size_t)base * 2048 + (size_t)threadIdx.x * 8;
  float4 a = *(const float4*)(s + idx);
  float4 b = *(const float4*)(s + idx + 4);
  short8 o;
  o[0] = (short)f2bf(a.x); o[1] = (short)f2bf(a.y); o[2] = (short)f2bf(a.z); o[3] = (short)f2bf(a.w);
  o[4] = (short)f2bf(b.x); o[5] = (short)f2bf(b.y); o[6] = (short)f2bf(b.z); o[7] = (short)f2bf(b.w);
  *(short8*)(d + idx) = o;
}

// ================= shared 128x128 GEMM core (BK=64, 4 waves, acc 4x4) =================
#define GEMM_CORE(A_, Bw_)                                                              \
  f32x4 acc[4][4];                                                                      \
  _Pragma("unroll") for (int m = 0; m < 4; ++m)                                         \
    _Pragma("unroll") for (int n = 0; n < 4; ++n)                                       \
      acc[m][n] = (f32x4){0.f, 0.f, 0.f, 0.f};                                          \
  for (int k0 = 0; k0 < 1024; k0 += 64) {                                               \
    _Pragma("unroll") for (int p = 0; p < 4; ++p) {                                     \
      int idx = p * 256 + tid;                                                          \
      int row = idx >> 3, slot = idx & 7;                                               \
      gl_lds16(A_ + (size_t)(m0 + row) * 1024 + k0 + ((slot ^ (row & 7)) * 8), As + idx * 8); \
    }                                                                                   \
    _Pragma("unroll") for (int p = 0; p < 4; ++p) {                                     \
      int idx = p * 256 + tid;                                                          \
      int row = idx >> 3, slot = idx & 7;                                               \
      gl_lds16(Bw_ + (size_t)(n0 + row) * 1024 + k0 + ((slot ^ (row & 7)) * 8), Bs + idx * 8); \
    }                                                                                   \
    __syncthreads();                                                                    \
    _Pragma("unroll") for (int kk = 0; kk < 2; ++kk) {                                  \
      short8 af[4], bf[4];                                                              \
      _Pragma("unroll") for (int m = 0; m < 4; ++m) {                                   \
        int row = wrow + m * 16 + c;                                                    \
        af[m] = *(const short8*)(As + row * 64 + (((kk * 4 + g) ^ (row & 7)) * 8));     \
      }                                                                                 \
      _Pragma("unroll") for (int n = 0; n < 4; ++n) {                                   \
        int row = wcol + n * 16 + c;                                                    \
        bf[n] = *(const short8*)(Bs + row * 64 + (((kk * 4 + g) ^ (row & 7)) * 8));     \
      }                                                                                 \
      _Pragma("unroll") for (int m = 0; m < 4; ++m)                                     \
        _Pragma("unroll") for (int n = 0; n < 4; ++n)                                   \
          acc[m][n] = __builtin_amdgcn_mfma_f32_16x16x32_bf16(af[m], bf[n], acc[m][n], 0, 0, 0); \
    }                                                                                   \
    __syncthreads();                                                                    \
  }

// ---------------- merged projection GEMMs: z=0 K->Kf (scaled by SC2), z=1 V->Vf, z=2 Q->Ql ----------------
__global__ __launch_bounds__(256, 3)
void proj_qkv(const u16* __restrict__ qb, const u16* __restrict__ kb, const u16* __restrict__ vb,
              const u16* __restrict__ wqb, const u16* __restrict__ wkb, const u16* __restrict__ wvb,
              const float* __restrict__ bq, const float* __restrict__ bk, const float* __restrict__ bv,
              u16* __restrict__ Ql, u16* __restrict__ Kf, u16* __restrict__ Vf) {
  __shared__ u16 As[128 * 64];
  __shared__ u16 Bs[128 * 64];
  const int z = blockIdx.z;
  const u16* A  = (z == 0) ? kb : (z == 1) ? vb : qb;
  const u16* Bw = (z == 0) ? wkb : (z == 1) ? wvb : wqb;
  const float* bias = (z == 0) ? bk : (z == 1) ? bv : bq;
  const int tid = threadIdx.x;
  const int l = tid & 63, w = tid >> 6;
  const int m0 = blockIdx.x * 128, n0 = blockIdx.y * 128;
  const int wrow = (w & 1) * 64, wcol = (w >> 1) * 64;
  const int g = l >> 4, c = l & 15;

  GEMM_CORE(A, Bw)

#pragma unroll
  for (int n = 0; n < 4; ++n) {
    int col = n0 + wcol + n * 16 + c;
    float bv_ = bias[col];
    int hh = col >> 6, dd = col & 63;
#pragma unroll
    for (int m = 0; m < 4; ++m) {
#pragma unroll
      for (int r = 0; r < 4; ++r) {
        int rowg = m0 + wrow + m * 16 + g * 4 + r;
        float val = acc[m][n][r] + bv_;
        int bb = rowg >> 10, jj = rowg & 1023;
        if (z == 0)      Kf[KFoff(bb, hh, jj, dd)] = f2bf(val * SC2);
        else if (z == 1) Vf[VFoff(bb, hh, jj, dd)] = f2bf(val);
        else             Ql[(size_t)rowg * 1024 + col] = f2bf(val);
      }
    }
  }
}

// ---------------- fused focus GEMM: c = tanh(Ql@Wfq^T + gbias); P,IZ reduced in-register ----------------
__global__ __launch_bounds__(256, 2)
void gemm_tanh_pz(const u16* __restrict__ A, const u16* __restrict__ Bw,
                  const float* __restrict__ gb,
                  const float* __restrict__ up, const float* __restrict__ uz,
                  float* __restrict__ Pout, float* __restrict__ IZout) {
  __shared__ u16 As[128 * 64];
  __shared__ u16 Bs[128 * 64];
  const int tid = threadIdx.x;
  const int l = tid & 63, w = tid >> 6;
  const int m0 = blockIdx.x * 128, n0 = blockIdx.y * 128;
  const int wrow = (w & 1) * 64, wcol = (w >> 1) * 64;
  const int g = l >> 4, c = l & 15;

  GEMM_CORE(A, Bw)

  const int hglob = (n0 + wcol) >> 6;
  const int batch = m0 >> 10;
  float upv[4], uzv[4], gbv[4];
#pragma unroll
  for (int n = 0; n < 4; ++n) {
    int col = n0 + wcol + n * 16 + c;
    upv[n] = up[col];
    uzv[n] = uz[col];
    gbv[n] = gb[batch * 1024 + col];
  }
#pragma unroll
  for (int m = 0; m < 4; ++m) {
#pragma unroll
    for (int r = 0; r < 4; ++r) {
      float pp = 0.f, zz = 0.f;
#pragma unroll
      for (int n = 0; n < 4; ++n) {
        float cval = tanhf(acc[m][n][r] + gbv[n]);
        pp += cval * upv[n];
        zz += cval * uzv[n];
      }
#pragma unroll
      for (int d = 1; d < 16; d <<= 1) {
        pp += __shfl_xor(pp, d);
        zz += __shfl_xor(zz, d);
      }
      if (c == 0) {
        int rowg = m0 + wrow + m * 16 + g * 4 + r;
        int qi = rowg & 1023;
        float Pv = 1024.f / (1.f + __expf(-pp));
        float Zv = 1024.f / (1.f + __expf(-zz));
        size_t o = (size_t)(batch * 16 + hglob) * 1024 + qi;
        Pout[o] = Pv;
        IZout[o] = 2.0f / (Zv * Zv) * L2E;
      }
    }
  }
}

// ---------------- partial column sums of q_lin for glo ----------------
__global__ __launch_bounds__(128) void glo_part_k(const u16* __restrict__ qlin, float* __restrict__ gpart) {
  int b = blockIdx.x & 3, seg = blockIdx.x >> 2;
  int t = threadIdx.x;
  float acc[8] = {0, 0, 0, 0, 0, 0, 0, 0};
  for (int s = seg * 16; s < seg * 16 + 16; ++s) {
    short8 v = *(const short8*)(qlin + (size_t)(b * 1024 + s) * 1024 + t * 8);
#pragma unroll
    for (int j = 0; j < 8; ++j) acc[j] += bf2f((u16)v[j]);
  }
#pragma unroll
  for (int j = 0; j < 8; ++j) gpart[(size_t)(seg * 4 + b) * 1024 + t * 8 + j] = acc[j];
}

// ---------------- glo_reduce: 8 independent chains ----------------
__global__ __launch_bounds__(128) void glo_reduce(const float* __restrict__ gpart, float* __restrict__ glo) {
  int b = blockIdx.x & 3, cc = blockIdx.x >> 2;
  int col = cc * 128 + threadIdx.x;
  float a[8] = {0, 0, 0, 0, 0, 0, 0, 0};
#pragma unroll
  for (int s8 = 0; s8 < 8; ++s8) {
#pragma unroll
    for (int s = 0; s < 8; ++s)
      a[s] += gpart[(size_t)((s8 * 8 + s) * 4 + b) * 1024 + col];
  }
  float t = ((a[0] + a[1]) + (a[2] + a[3])) + ((a[4] + a[5]) + (a[6] + a[7]));
  glo[b * 1024 + col] = t * (1.0f / 1024.0f);
}

// ---------------- gbias ----------------
__global__ __launch_bounds__(256) void gbias_k(const float* __restrict__ glo, const float* __restrict__ Wfg,
                                               const float* __restrict__ bfq, const float* __restrict__ bfg,
                                               float* __restrict__ gbias) {
  __shared__ float glo_l[4096];
  int tid = threadIdx.x;
  for (int idx = tid; idx < 4096; idx += 256) glo_l[idx] = glo[idx];
  __syncthreads();
  int w = tid >> 6, l = tid & 63;
#pragma unroll
  for (int i = 0; i < 4; ++i) {
    int n = blockIdx.x * 16 + w * 4 + i;
    float a0 = 0, a1 = 0, a2 = 0, a3 = 0;
#pragma unroll
    for (int kk = 0; kk < 4; ++kk) {
      int k = kk * 256 + l * 4;
      float4 wv = *(const float4*)(Wfg + (size_t)n * 1024 + k);
      float4 g0 = *(const float4*)(&glo_l[k]);
      float4 g1 = *(const float4*)(&glo_l[1024 + k]);
      float4 g2 = *(const float4*)(&glo_l[2048 + k]);
      float4 g3 = *(const float4*)(&glo_l[3072 + k]);
      a0 += wv.x * g0.x + wv.y * g0.y + wv.z * g0.z + wv.w * g0.w;
      a1 += wv.x * g1.x + wv.y * g1.y + wv.z * g1.z + wv.w * g1.w;
      a2 += wv.x * g2.x + wv.y * g2.y + wv.z * g2.z + wv.w * g2.w;
      a3 += wv.x * g3.x + wv.y * g3.y + wv.z * g3.z + wv.w * g3.w;
    }
#pragma unroll
    for (int d = 1; d < 64; d <<= 1) {
      a0 += __shfl_xor(a0, d); a1 += __shfl_xor(a1, d);
      a2 += __shfl_xor(a2, d); a3 += __shfl_xor(a3, d);
    }
    if (l == 0) {
      float bb = bfq[n] + bfg[n];
      gbias[n] = a0 + bb; gbias[1024 + n] = a1 + bb;
      gbias[2048 + n] = a2 + bb; gbias[3072 + n] = a3 + bb;
    }
  }
}

// ---------------- flash attention: 32-j chunks, 4 blocks/CU, aug-MFMA scores, counted vmcnt ----------------
template<int WP>
__global__ __launch_bounds__(512, 4)
void attn_flash(const u16* __restrict__ Qlin, const u16* __restrict__ Kf, const u16* __restrict__ Vf,
                const float* __restrict__ Pbuf, const float* __restrict__ IZbuf,
                u16* __restrict__ xbuf, float* __restrict__ Mbuf, float* __restrict__ iLbuf,
                u16* __restrict__ Pall, float* __restrict__ mch) {
  __shared__ u16 sm16[18432];   // 36,864B: buf i at i*5120 (K+aug 3072 + V 2048 u16); ps at 10240 (8192 u16)

  const int tid = threadIdx.x;
  const int l = tid & 63, w = tid >> 6;
  const int g = l >> 4, c = l & 15;
  const int bid = blockIdx.x;
  const int bh = (bid & 7) + ((bid >> 6) << 3);
  const int qc = (bid >> 3) & 7;
  const int b = bh >> 4, h = bh & 15;
  const int q0w = qc * 128 + w * 16;

  char* ps_ = (char*)(sm16 + 10240) + w * 2048;

  const u16* KfH = Kf + (size_t)bh * 98304;
  const u16* VfH = Vf + (size_t)bh * 65536;

  const u16* qrow = Qlin + (size_t)(b * 1024 + q0w + c) * 1024 + h * 64 + g * 8;
  short8 af0 = *(const short8*)qrow;
  short8 af1 = *(const short8*)(qrow + 32);
  short8 af2 = (short8){0, 0, 0, 0, 0, 0, 0, 0};
  if (g == 0) {
    float Pc = Pbuf[(size_t)bh * 1024 + q0w + c] - 512.0f;
    float Ic = IZbuf[(size_t)bh * 1024 + q0w + c];
    af2[0] = (short)f2bf(-Ic);
    af2[1] = (short)f2bf(2.0f * Pc * Ic);
    af2[2] = (short)f2bf(-Pc * Pc * Ic);
    af2[3] = (short)f2bf(1.0f);
  }

  float m[4], lsum[4];
  f32x4 xacc[4];
#pragma unroll
  for (int r = 0; r < 4; ++r) { m[r] = -3.0e38f; lsum[r] = 0.f; }
#pragma unroll
  for (int dt = 0; dt < 4; ++dt) xacc[dt] = (f32x4){0.f, 0.f, 0.f, 0.f};

  // stage chunk jn (32 j): K+aug 3072 u16 contiguous + V 4x512 u16. 640 x 16B loads:
  // waves 0-1 issue 2 loads, waves 2-7 issue 1.
  auto stage = [&](int jn, u16* nb) {
    if (tid < 384) {
      gl_lds16(KfH + (size_t)jn * 3072 + tid * 8, nb + tid * 8);
    } else {
      int vi = tid - 384;   // 0..127
      gl_lds16(VfH + ((size_t)((vi >> 6) * 32 + jn) * 512) + (vi & 63) * 8, nb + 3072 + vi * 8);
    }
    if (tid < 128) {
      int vi = tid + 128;   // 128..255
      gl_lds16(VfH + ((size_t)((vi >> 6) * 32 + jn) * 512) + (vi & 63) * 8, nb + 3072 + vi * 8);
    }
  };

  stage(0, sm16);
  __syncthreads();

  for (int jc = 0; jc < 32; ++jc) {
    u16* Ksb = sm16 + (jc & 1) * 5120;
    u16* Vsb = Ksb + 3072;
    if (jc < 31) stage(jc + 1, sm16 + ((jc + 1) & 1) * 5120);

    // ---- QK^T + G + mask via 3 MFMAs per 16-j tile (log2-space scores) ----
    f32x4 sc[2];
    float cm[4] = {-3.0e38f, -3.0e38f, -3.0e38f, -3.0e38f};
    __builtin_amdgcn_s_setprio(1);
#pragma unroll
    for (int t = 0; t < 2; ++t) {
      short8 b0 = *(const short8*)(Ksb + (t * 3 + 0) * 512 + l * 8);
      short8 b1 = *(const short8*)(Ksb + (t * 3 + 1) * 512 + l * 8);
      short8 b2 = *(const short8*)(Ksb + (t * 3 + 2) * 512 + l * 8);
      f32x4 z = (f32x4){0.f, 0.f, 0.f, 0.f};
      z = __builtin_amdgcn_mfma_f32_16x16x32_bf16(af0, b0, z, 0, 0, 0);
      z = __builtin_amdgcn_mfma_f32_16x16x32_bf16(af1, b1, z, 0, 0, 0);
      z = __builtin_amdgcn_mfma_f32_16x16x32_bf16(af2, b2, z, 0, 0, 0);
      sc[t] = z;
#pragma unroll
      for (int r = 0; r < 4; ++r) cm[r] = fmaxf(cm[r], z[r]);
    }
    __builtin_amdgcn_s_setprio(0);
#pragma unroll
    for (int d = 1; d < 16; d <<= 1)
#pragma unroll
      for (int r = 0; r < 4; ++r) cm[r] = fmaxf(cm[r], __shfl_xor(cm[r], d));
    float scale[4], ps[4];
#pragma unroll
    for (int r = 0; r < 4; ++r) {
      float nm = fmaxf(m[r], cm[r]);
      scale[r] = fexp2(m[r] - nm);
      m[r] = nm;
      ps[r] = 0.f;
    }
#pragma unroll
    for (int t = 0; t < 2; ++t) {
#pragma unroll
      for (int r = 0; r < 4; ++r) {
        float p = fexp2(sc[t][r] - m[r]);
        ps[r] += p;
        int row = g * 4 + r;
        int byte = (row * 128 + (t * 16 + c) * 2) ^ ((row & 7) << 4);
        *(u16*)(ps_ + byte) = f2bf(p);
      }
    }
#pragma unroll
    for (int r = 0; r < 4; ++r) {
      lsum[r] = lsum[r] * scale[r] + ps[r];
#pragma unroll
      for (int dt = 0; dt < 4; ++dt) xacc[dt][r] *= scale[r];
    }
    if (WP && c == 0) {
      f32x4 mv;
      mv.x = m[0]; mv.y = m[1]; mv.z = m[2]; mv.w = m[3];
      *(f32x4*)(mch + ((size_t)bh * 32 + jc) * 1024 + q0w + g * 4) = mv;
    }
    if (WP) {
      int i = l * 8;
      int row = i >> 5, col = i & 31;
      int byte = (row * 128 + col * 2) ^ ((row & 7) << 4);
      short8 v = *(const short8*)(ps_ + byte);
      *(short8*)(Pall + (((size_t)bh * 32 + jc) * 1024 + q0w + row) * 32 + col) = v;
    }
    // ---- PV: single k=32 fragment per d-tile ----
    short8 pa;
    {
      int abyte = (c * 128 + (g * 8) * 2) ^ ((c & 7) << 4);
      pa = *(const short8*)(ps_ + abyte);
    }
    __builtin_amdgcn_s_setprio(1);
#pragma unroll
    for (int dt = 0; dt < 4; ++dt) {
      short8 vb = *(const short8*)(Vsb + dt * 512 + l * 8);
      xacc[dt] = __builtin_amdgcn_mfma_f32_16x16x32_bf16(pa, vb, xacc[dt], 0, 0, 0);
    }
    __builtin_amdgcn_s_setprio(0);
    // ---- counted wait: retire stage(jc+1) loads (FIFO before this chunk's 2 stores) ----
    if (jc < 31) {
      if (WP) asm volatile("s_waitcnt vmcnt(2)" ::: "memory");
      else    asm volatile("s_waitcnt vmcnt(0)" ::: "memory");
    }
    __builtin_amdgcn_sched_barrier(0);
    __builtin_amdgcn_s_barrier();
    __builtin_amdgcn_sched_barrier(0);
  }

  // ---- finalize ----
#pragma unroll
  for (int d = 1; d < 16; d <<= 1)
#pragma unroll
    for (int r = 0; r < 4; ++r) lsum[r] += __shfl_xor(lsum[r], d);
  float iLr[4];
#pragma unroll
  for (int r = 0; r < 4; ++r) iLr[r] = 1.0f / lsum[r];
  if (c == 0) {
#pragma unroll
    for (int r = 0; r < 4; ++r) {
      size_t o = (size_t)bh * 1024 + q0w + g * 4 + r;
      Mbuf[o] = m[r];
      iLbuf[o] = iLr[r];
    }
  }
  // ---- x epilogue (xs reuses sm16; all K/V reads done at final barrier) ----
  float* xs = (float*)sm16 + w * 1024;
#pragma unroll
  for (int dt = 0; dt < 4; ++dt)
#pragma unroll
    for (int r = 0; r < 4; ++r)
      xs[(g * 4 + r) * 64 + dt * 16 + c] = xacc[dt][r] * iLr[r];
#pragma unroll
  for (int k2 = 0; k2 < 4; ++k2) {
    int i = k2 * 256 + l * 4;
    int row = i >> 6, d0 = i & 63;
    f32x4 xv = *(const f32x4*)(xs + i);
    short4v o;
    o[0] = (short)f2bf(xv.x); o[1] = (short)f2bf(xv.y);
    o[2] = (short)f2bf(xv.z); o[3] = (short)f2bf(xv.w);
    *(short4v*)(xbuf + (size_t)(b * 1024 + q0w + row) * 1024 + h * 64 + d0) = o;
  }
}

// ---------------- merged epilogue: blocks [0,256) = W_o GEMM (f32 out); rest = meansum ----------------
__global__ __launch_bounds__(256, 3)
void epilogue_k(const u16* __restrict__ A, const u16* __restrict__ Bw,
                const float* __restrict__ bias, float* __restrict__ out0,
                const u16* __restrict__ Pall, const float* __restrict__ iLbuf,
                const float* __restrict__ Mbuf, const float* __restrict__ mchb,
                float* __restrict__ out2, int usePall) {
  __shared__ u16 As[128 * 64];
  __shared__ u16 Bs[128 * 64];
  const int bid = blockIdx.x;
  const int tid = threadIdx.x;
  if (bid >= 256) {
    if (!usePall) return;
    int bq = (bid - 256) * 2 + (tid >> 7);
    int b = bq >> 10, q = bq & 1023;
    int j = (tid & 127) * 8;
    int jc = j >> 5, jin = j & 31;
    float acc[8] = {0, 0, 0, 0, 0, 0, 0, 0};
    for (int h = 0; h < 16; ++h) {
      int bh = b * 16 + h;
      float M = Mbuf[(size_t)bh * 1024 + q];
      float iLh = iLbuf[(size_t)bh * 1024 + q];
      float mc = mchb[((size_t)bh * 32 + jc) * 1024 + q];
      float f = fexp2(mc - M) * iLh;
      short8 p = *(const short8*)(Pall + (((size_t)bh * 32 + jc) * 1024 + q) * 32 + jin);
#pragma unroll
      for (int i = 0; i < 8; ++i) acc[i] = fmaf(bf2f((u16)p[i]), f, acc[i]);
    }
    float* dst = out2 + (size_t)bq * 1024 + j;
#pragma unroll
    for (int i = 0; i < 8; ++i) dst[i] = acc[i] * 0.0625f;
    return;
  }
  // ---- GEMM path (128x128) ----
  const int l = tid & 63, w = tid >> 6;
  const int m0 = (bid & 31) * 128, n0 = (bid >> 5) * 128;
  const int wrow = (w & 1) * 64, wcol = (w >> 1) * 64;
  const int g = l >> 4, c = l & 15;

  GEMM_CORE(A, Bw)

#pragma unroll
  for (int n = 0; n < 4; ++n) {
    int col = n0 + wcol + n * 16 + c;
    float bv = bias[col];
#pragma unroll
    for (int m = 0; m < 4; ++m) {
#pragma unroll
      for (int r = 0; r < 4; ++r) {
        int rowg = m0 + wrow + m * 16 + g * 4 + r;
        out0[(size_t)rowg * 1024 + col] = acc[m][n][r] + bv;
      }
    }
  }
}

// ---------------- fallback mean: recompute QK^T from K fragments (exp2-space, K pre-scaled) ----------------
__global__ __launch_bounds__(512, 4)
void attn_mean(const u16* __restrict__ Qlin, const u16* __restrict__ Kf,
               const float* __restrict__ Pbuf, const float* __restrict__ IZbuf,
               const float* __restrict__ Mbuf, const float* __restrict__ iLbuf,
               const int* __restrict__ mask,
               float* __restrict__ out2) {
  const int tid = threadIdx.x;
  const int l = tid & 63, w = tid >> 6;
  const int g = l >> 4, c = l & 15;
  int chunk = (blockIdx.x % 8) * 64 + blockIdx.x / 8;
  const int b = chunk >> 7;
  const int qt = (chunk & 127) >> 1;
  const int jh = chunk & 1;
  const int q0 = qt * 16;
  const int jbase = jh * 512 + w * 64;

  float mb[4];
#pragma unroll
  for (int t = 0; t < 4; ++t)
    mb[t] = (mask[b * 1024 + jbase + t * 16 + c] == 0) ? -1.4e15f : 0.0f;

  f32x4 macc[4];
#pragma unroll
  for (int t = 0; t < 4; ++t) macc[t] = (f32x4){0.f, 0.f, 0.f, 0.f};

  for (int h = 0; h < 16; ++h) {
    const u16* qrow = Qlin + (size_t)(b * 1024 + q0 + c) * 1024 + h * 64 + g * 8;
    short8 af0 = *(const short8*)qrow;
    short8 af1 = *(const short8*)(qrow + 32);
    const u16* kb2 = Kf + ((size_t)((b * 16 + h) * 64 + jh * 32 + w * 4) * 3) * 512 + l * 8;
    float Pq[4], IZq[4], Mq[4], iLq[4];
#pragma unroll
    for (int r = 0; r < 4; ++r) {
      size_t o = (size_t)(b * 16 + h) * 1024 + q0 + g * 4 + r;
      Pq[r] = Pbuf[o]; IZq[r] = IZbuf[o]; Mq[r] = Mbuf[o]; iLq[r] = iLbuf[o] * 0.0625f;
    }
#pragma unroll
    for (int t = 0; t < 4; ++t) {
      short8 bf0 = *(const short8*)(kb2 + (t * 3 + 0) * 512);
      short8 bf1 = *(const short8*)(kb2 + (t * 3 + 1) * 512);
      f32x4 z = (f32x4){0.f, 0.f, 0.f, 0.f};
      z = __builtin_amdgcn_mfma_f32_16x16x32_bf16(af0, bf0, z, 0, 0, 0);
      z = __builtin_amdgcn_mfma_f32_16x16x32_bf16(af1, bf1, z, 0, 0, 0);
      float jf = (float)(jbase + t * 16 + c);
#pragma unroll
      for (int r = 0; r < 4; ++r) {
        float diff = jf - Pq[r];
        float s = z[r] + mb[t] - diff * diff * IZq[r];
        macc[t][r] += fexp2(s - Mq[r]) * iLq[r];
      }
    }
  }
#pragma unroll
  for (int t = 0; t < 4; ++t) {
#pragma unroll
    for (int r = 0; r < 4; ++r)
      out2[(size_t)(b * 1024 + q0 + g * 4 + r) * 1024 + jbase + t * 16 + c] = macc[t][r];
  }
}

// ---------------- host ----------------
extern "C" void kernel_launch(void* const* d_in, const int* in_sizes, int n_in,
                              void* d_out, int out_size, void* d_ws, size_t ws_size,
                              hipStream_t stream) {
  const float* q   = (const float*)d_in[0];
  const float* k   = (const float*)d_in[1];
  const float* v   = (const float*)d_in[2];
  const int*   msk = (const int*)d_in[3];
  const float* Wk  = (const float*)d_in[4];  const float* bk  = (const float*)d_in[5];
  const float* Wv  = (const float*)d_in[6];  const float* bv  = (const float*)d_in[7];
  const float* Wq  = (const float*)d_in[8];  const float* bq  = (const float*)d_in[9];
  const float* Wo  = (const float*)d_in[10]; const float* bo  = (const float*)d_in[11];
  const float* Wfq = (const float*)d_in[12]; const float* bfq = (const float*)d_in[13];
  const float* Wfg = (const float*)d_in[14]; const float* bfg = (const float*)d_in[15];
  const float* up  = (const float*)d_in[16]; const float* uz  = (const float*)d_in[17];

  const size_t MB = 1u << 20;
  char* base = (char*)d_ws;
  char* p = base;
  auto take = [&](size_t n) { char* r = p; p += (n + 255) & ~(size_t)255; return r; };
  // Long-lived zone (live through attention):
  u16* Kf   = (u16*)take(12 * MB);
  u16* Ql   = (u16*)take(8 * MB);
  u16* Vf   = (u16*)take(8 * MB);
  u16* xb   = (u16*)take(8 * MB);
  u16* wob  = (u16*)take(2 * MB);
  float* Pb    = (float*)take((size_t)65536 * 4);
  float* IZb   = (float*)take((size_t)65536 * 4);
  float* Mb    = (float*)take((size_t)65536 * 4);
  float* iLb   = (float*)take((size_t)65536 * 4);
  float* mch   = (float*)take((size_t)64 * 32 * 1024 * 4);   // 8MB
  float* gpart = (float*)take((size_t)64 * 4 * 1024 * 4);    // 1MB
  float* glo   = (float*)take(4096 * 4);
  float* gbias = (float*)take(4096 * 4);
  // Dead-by-attention pool (aliased by Pall):
  size_t pool_off = (size_t)(p - base);
  u16* qb   = (u16*)take(8 * MB);
  u16* kb   = (u16*)take(8 * MB);
  u16* vb   = (u16*)take(8 * MB);
  u16* wkb  = (u16*)take(2 * MB);
  u16* wvb  = (u16*)take(2 * MB);
  u16* wqb  = (u16*)take(2 * MB);
  u16* wfqb = (u16*)take(2 * MB);
  u16* Pall = (u16*)(base + pool_off);
  int usePall = (ws_size >= pool_off + (size_t)128 * MB) ? 1 : 0;

  float* out0 = (float*)d_out;
  float* out2 = out0 + (size_t)4 * 1024 * 1024;

  cvt_all<<<8960, 256, 0, stream>>>(q, k, v, Wk, Wv, Wq, Wfq, Wo,
                                    qb, kb, vb, wkb, wvb, wqb, wfqb, wob, msk, Kf);
  dim3 gg3(32, 8, 3);
  proj_qkv<<<gg3, 256, 0, stream>>>(qb, kb, vb, wqb, wkb, wvb, bq, bk, bv, Ql, Kf, Vf);
  dim3 gg(32, 8);
  glo_part_k<<<256, 128, 0, stream>>>(Ql, gpart);
  glo_reduce<<<32, 128, 0, stream>>>(gpart, glo);
  gbias_k<<<64, 256, 0, stream>>>(glo, Wfg, bfq, bfg, gbias);
  gemm_tanh_pz<<<gg, 256, 0, stream>>>(Ql, wfqb, gbias, up, uz, Pb, IZb);
  if (usePall) {
    attn_flash<1><<<512, 512, 0, stream>>>(Ql, Kf, Vf, Pb, IZb, xb, Mb, iLb, Pall, mch);
    epilogue_k<<<2304, 256, 0, stream>>>(xb, wob, bo, out0, Pall, iLb, Mb, mch, out2, 1);
  } else {
    attn_flash<0><<<512, 512, 0, stream>>>(Ql, Kf, Vf, Pb, IZb, xb, Mb, iLb, Pall, mch);
    attn_mean<<<512, 512, 0, stream>>>(Ql, Kf, Pb, IZb, Mb, iLb, msk, out2);
    epilogue_k<<<256, 256, 0, stream>>>(xb, wob, bo, out0, Pall, iLb, Mb, mch, out2, 0);
  }
}

// Round 21
// 184.956 us; speedup vs baseline: 1.1173x; 1.1173x over previous
//
#include <hip/hip_runtime.h>
#include <hip/hip_bf16.h>
#include <math.h>

typedef __attribute__((ext_vector_type(8))) short short8;
typedef __attribute__((ext_vector_type(4))) short short4v;
typedef __attribute__((ext_vector_type(4))) float f32x4;
typedef unsigned short u16;

#define SC2 0.18033688011112042f   // 0.125 * log2(e)
#define L2E 1.4426950408889634f

__device__ __forceinline__ u16 f2bf(float f) {
  union { float f; unsigned u; } v; v.f = f;
  unsigned u = v.u + 0x7fffu + ((v.u >> 16) & 1u);
  return (u16)(u >> 16);
}
__device__ __forceinline__ float bf2f(u16 h) {
  union { unsigned u; float f; } v; v.u = ((unsigned)h) << 16;
  return v.f;
}
__device__ __forceinline__ float fexp2(float x) {
  float r; asm("v_exp_f32 %0, %1" : "=v"(r) : "v"(x)); return r;
}
__device__ __forceinline__ void gl_lds16(const u16* g, u16* l) {
  __builtin_amdgcn_global_load_lds(
      (const __attribute__((address_space(1))) void*)g,
      (__attribute__((address_space(3))) void*)l, 16, 0, 0);
}

// K fragment layout (3 k-subtiles): (b,h,j,d) -> ((((bh)*64 + j/16)*3 + d/32)*64 + ((d>>3)&3)*16 + (j&15))*8 + (d&7)
__device__ __forceinline__ size_t KFoff(int b, int h, int j, int d) {
  return ((((size_t)(b * 16 + h) * 64 + (j >> 4)) * 3 + (d >> 5)) * 64
          + ((d >> 3) & 3) * 16 + (j & 15)) * 8 + (d & 7);
}
// V fragment layout: (b,h,j,d) -> ((((bh)*4 + d/16)*32 + j/32)*64 + ((j>>3)&3)*16 + (d&15))*8 + (j&7)
__device__ __forceinline__ size_t VFoff(int b, int h, int j, int d) {
  return ((((size_t)(b * 16 + h) * 4 + (d >> 4)) * 32 + (j >> 5)) * 64
          + ((j >> 3) & 3) * 16 + (d & 15)) * 8 + (j & 7);
}

// ---------------- convert f32 -> bf16 (and blocks >= 8704: kaug fill) ----------------
__global__ __launch_bounds__(256) void cvt_all(
    const float* __restrict__ q, const float* __restrict__ k, const float* __restrict__ v,
    const float* __restrict__ w0, const float* __restrict__ w1, const float* __restrict__ w2,
    const float* __restrict__ w3, const float* __restrict__ w4,
    u16* __restrict__ qb, u16* __restrict__ kb, u16* __restrict__ vb,
    u16* __restrict__ w0b, u16* __restrict__ w1b, u16* __restrict__ w2b,
    u16* __restrict__ w3b, u16* __restrict__ w4b,
    const int* __restrict__ mask, u16* __restrict__ Kf) {
  int bid = blockIdx.x;
  if (bid >= 8704) {
    int bidx = bid - 8704;
    int b = bidx >> 6, jt = bidx & 63;
    int t = threadIdx.x;
    int h = t >> 4, jj = t & 15;
    int j = jt * 16 + jj;
    float jc = (float)(j - 512);
    float mbv = (mask[b * 1024 + j] == 0) ? -1.4e15f : 0.0f;
    u16* base = Kf + ((size_t)((b * 16 + h) * 64 + jt) * 3 + 2) * 512;
    short8 z8 = (short8){0, 0, 0, 0, 0, 0, 0, 0};
    short8 f8 = z8;
    f8[0] = (short)f2bf(jc * jc);
    f8[1] = (short)f2bf(jc);
    f8[2] = (short)f2bf(1.0f);
    f8[3] = (short)f2bf(mbv);
    *(short8*)(base + jj * 8) = f8;
    *(short8*)(base + 128 + jj * 8) = z8;
    *(short8*)(base + 256 + jj * 8) = z8;
    *(short8*)(base + 384 + jj * 8) = z8;
    return;
  }
  const float* s; u16* d; int base;
  if (bid < 2048)      { s = q; d = qb; base = bid; }
  else if (bid < 4096) { s = k; d = kb; base = bid - 2048; }
  else if (bid < 6144) { s = v; d = vb; base = bid - 4096; }
  else {
    int t2 = bid - 6144; int wi = t2 >> 9; base = t2 & 511;
    if (wi == 0)      { s = w0; d = w0b; }
    else if (wi == 1) { s = w1; d = w1b; }
    else if (wi == 2) { s = w2; d = w2b; }
    else if (wi == 3) { s = w3; d = w3b; }
    else              { s = w4; d = w4b; }
  }
  size_t idx = (size_t)base * 2048 + (size_t)threadIdx.x * 8;
  float4 a = *(const float4*)(s + idx);
  float4 b = *(const float4*)(s + idx + 4);
  short8 o;
  o[0] = (short)f2bf(a.x); o[1] = (short)f2bf(a.y); o[2] = (short)f2bf(a.z); o[3] = (short)f2bf(a.w);
  o[4] = (short)f2bf(b.x); o[5] = (short)f2bf(b.y); o[6] = (short)f2bf(b.z); o[7] = (short)f2bf(b.w);
  *(short8*)(d + idx) = o;
}

// ================= shared 128x128 GEMM core (BK=64, 4 waves, acc 4x4) =================
#define GEMM_CORE(A_, Bw_)                                                              \
  f32x4 acc[4][4];                                                                      \
  _Pragma("unroll") for (int m = 0; m < 4; ++m)                                         \
    _Pragma("unroll") for (int n = 0; n < 4; ++n)                                       \
      acc[m][n] = (f32x4){0.f, 0.f, 0.f, 0.f};                                          \
  for (int k0 = 0; k0 < 1024; k0 += 64) {                                               \
    _Pragma("unroll") for (int p = 0; p < 4; ++p) {                                     \
      int idx = p * 256 + tid;                                                          \
      int row = idx >> 3, slot = idx & 7;                                               \
      gl_lds16(A_ + (size_t)(m0 + row) * 1024 + k0 + ((slot ^ (row & 7)) * 8), As + idx * 8); \
    }                                                                                   \
    _Pragma("unroll") for (int p = 0; p < 4; ++p) {                                     \
      int idx = p * 256 + tid;                                                          \
      int row = idx >> 3, slot = idx & 7;                                               \
      gl_lds16(Bw_ + (size_t)(n0 + row) * 1024 + k0 + ((slot ^ (row & 7)) * 8), Bs + idx * 8); \
    }                                                                                   \
    __syncthreads();                                                                    \
    _Pragma("unroll") for (int kk = 0; kk < 2; ++kk) {                                  \
      short8 af[4], bf[4];                                                              \
      _Pragma("unroll") for (int m = 0; m < 4; ++m) {                                   \
        int row = wrow + m * 16 + c;                                                    \
        af[m] = *(const short8*)(As + row * 64 + (((kk * 4 + g) ^ (row & 7)) * 8));     \
      }                                                                                 \
      _Pragma("unroll") for (int n = 0; n < 4; ++n) {                                   \
        int row = wcol + n * 16 + c;                                                    \
        bf[n] = *(const short8*)(Bs + row * 64 + (((kk * 4 + g) ^ (row & 7)) * 8));     \
      }                                                                                 \
      _Pragma("unroll") for (int m = 0; m < 4; ++m)                                     \
        _Pragma("unroll") for (int n = 0; n < 4; ++n)                                   \
          acc[m][n] = __builtin_amdgcn_mfma_f32_16x16x32_bf16(af[m], bf[n], acc[m][n], 0, 0, 0); \
    }                                                                                   \
    __syncthreads();                                                                    \
  }

// ---------------- merged projection GEMMs: z=0 K->Kf (scaled by SC2), z=1 V->Vf, z=2 Q->Ql ----------------
__global__ __launch_bounds__(256, 3)
void proj_qkv(const u16* __restrict__ qb, const u16* __restrict__ kb, const u16* __restrict__ vb,
              const u16* __restrict__ wqb, const u16* __restrict__ wkb, const u16* __restrict__ wvb,
              const float* __restrict__ bq, const float* __restrict__ bk, const float* __restrict__ bv,
              u16* __restrict__ Ql, u16* __restrict__ Kf, u16* __restrict__ Vf) {
  __shared__ u16 As[128 * 64];
  __shared__ u16 Bs[128 * 64];
  const int z = blockIdx.z;
  const u16* A  = (z == 0) ? kb : (z == 1) ? vb : qb;
  const u16* Bw = (z == 0) ? wkb : (z == 1) ? wvb : wqb;
  const float* bias = (z == 0) ? bk : (z == 1) ? bv : bq;
  const int tid = threadIdx.x;
  const int l = tid & 63, w = tid >> 6;
  const int m0 = blockIdx.x * 128, n0 = blockIdx.y * 128;
  const int wrow = (w & 1) * 64, wcol = (w >> 1) * 64;
  const int g = l >> 4, c = l & 15;

  GEMM_CORE(A, Bw)

#pragma unroll
  for (int n = 0; n < 4; ++n) {
    int col = n0 + wcol + n * 16 + c;
    float bv_ = bias[col];
    int hh = col >> 6, dd = col & 63;
#pragma unroll
    for (int m = 0; m < 4; ++m) {
#pragma unroll
      for (int r = 0; r < 4; ++r) {
        int rowg = m0 + wrow + m * 16 + g * 4 + r;
        float val = acc[m][n][r] + bv_;
        int bb = rowg >> 10, jj = rowg & 1023;
        if (z == 0)      Kf[KFoff(bb, hh, jj, dd)] = f2bf(val * SC2);
        else if (z == 1) Vf[VFoff(bb, hh, jj, dd)] = f2bf(val);
        else             Ql[(size_t)rowg * 1024 + col] = f2bf(val);
      }
    }
  }
}

// ---------------- fused focus GEMM: c = tanh(Ql@Wfq^T + gbias); P,IZ reduced in-register ----------------
__global__ __launch_bounds__(256, 2)
void gemm_tanh_pz(const u16* __restrict__ A, const u16* __restrict__ Bw,
                  const float* __restrict__ gb,
                  const float* __restrict__ up, const float* __restrict__ uz,
                  float* __restrict__ Pout, float* __restrict__ IZout) {
  __shared__ u16 As[128 * 64];
  __shared__ u16 Bs[128 * 64];
  const int tid = threadIdx.x;
  const int l = tid & 63, w = tid >> 6;
  const int m0 = blockIdx.x * 128, n0 = blockIdx.y * 128;
  const int wrow = (w & 1) * 64, wcol = (w >> 1) * 64;
  const int g = l >> 4, c = l & 15;

  GEMM_CORE(A, Bw)

  const int hglob = (n0 + wcol) >> 6;
  const int batch = m0 >> 10;
  float upv[4], uzv[4], gbv[4];
#pragma unroll
  for (int n = 0; n < 4; ++n) {
    int col = n0 + wcol + n * 16 + c;
    upv[n] = up[col];
    uzv[n] = uz[col];
    gbv[n] = gb[batch * 1024 + col];
  }
#pragma unroll
  for (int m = 0; m < 4; ++m) {
#pragma unroll
    for (int r = 0; r < 4; ++r) {
      float pp = 0.f, zz = 0.f;
#pragma unroll
      for (int n = 0; n < 4; ++n) {
        float cval = tanhf(acc[m][n][r] + gbv[n]);
        pp += cval * upv[n];
        zz += cval * uzv[n];
      }
#pragma unroll
      for (int d = 1; d < 16; d <<= 1) {
        pp += __shfl_xor(pp, d);
        zz += __shfl_xor(zz, d);
      }
      if (c == 0) {
        int rowg = m0 + wrow + m * 16 + g * 4 + r;
        int qi = rowg & 1023;
        float Pv = 1024.f / (1.f + __expf(-pp));
        float Zv = 1024.f / (1.f + __expf(-zz));
        size_t o = (size_t)(batch * 16 + hglob) * 1024 + qi;
        Pout[o] = Pv;
        IZout[o] = 2.0f / (Zv * Zv) * L2E;
      }
    }
  }
}

// ---------------- partial column sums of q_lin for glo ----------------
__global__ __launch_bounds__(128) void glo_part_k(const u16* __restrict__ qlin, float* __restrict__ gpart) {
  int b = blockIdx.x & 3, seg = blockIdx.x >> 2;
  int t = threadIdx.x;
  float acc[8] = {0, 0, 0, 0, 0, 0, 0, 0};
  for (int s = seg * 16; s < seg * 16 + 16; ++s) {
    short8 v = *(const short8*)(qlin + (size_t)(b * 1024 + s) * 1024 + t * 8);
#pragma unroll
    for (int j = 0; j < 8; ++j) acc[j] += bf2f((u16)v[j]);
  }
#pragma unroll
  for (int j = 0; j < 8; ++j) gpart[(size_t)(seg * 4 + b) * 1024 + t * 8 + j] = acc[j];
}

// ---------------- glo_reduce: 8 independent chains ----------------
__global__ __launch_bounds__(128) void glo_reduce(const float* __restrict__ gpart, float* __restrict__ glo) {
  int b = blockIdx.x & 3, cc = blockIdx.x >> 2;
  int col = cc * 128 + threadIdx.x;
  float a[8] = {0, 0, 0, 0, 0, 0, 0, 0};
#pragma unroll
  for (int s8 = 0; s8 < 8; ++s8) {
#pragma unroll
    for (int s = 0; s < 8; ++s)
      a[s] += gpart[(size_t)((s8 * 8 + s) * 4 + b) * 1024 + col];
  }
  float t = ((a[0] + a[1]) + (a[2] + a[3])) + ((a[4] + a[5]) + (a[6] + a[7]));
  glo[b * 1024 + col] = t * (1.0f / 1024.0f);
}

// ---------------- gbias ----------------
__global__ __launch_bounds__(256) void gbias_k(const float* __restrict__ glo, const float* __restrict__ Wfg,
                                               const float* __restrict__ bfq, const float* __restrict__ bfg,
                                               float* __restrict__ gbias) {
  __shared__ float glo_l[4096];
  int tid = threadIdx.x;
  for (int idx = tid; idx < 4096; idx += 256) glo_l[idx] = glo[idx];
  __syncthreads();
  int w = tid >> 6, l = tid & 63;
#pragma unroll
  for (int i = 0; i < 4; ++i) {
    int n = blockIdx.x * 16 + w * 4 + i;
    float a0 = 0, a1 = 0, a2 = 0, a3 = 0;
#pragma unroll
    for (int kk = 0; kk < 4; ++kk) {
      int k = kk * 256 + l * 4;
      float4 wv = *(const float4*)(Wfg + (size_t)n * 1024 + k);
      float4 g0 = *(const float4*)(&glo_l[k]);
      float4 g1 = *(const float4*)(&glo_l[1024 + k]);
      float4 g2 = *(const float4*)(&glo_l[2048 + k]);
      float4 g3 = *(const float4*)(&glo_l[3072 + k]);
      a0 += wv.x * g0.x + wv.y * g0.y + wv.z * g0.z + wv.w * g0.w;
      a1 += wv.x * g1.x + wv.y * g1.y + wv.z * g1.z + wv.w * g1.w;
      a2 += wv.x * g2.x + wv.y * g2.y + wv.z * g2.z + wv.w * g2.w;
      a3 += wv.x * g3.x + wv.y * g3.y + wv.z * g3.z + wv.w * g3.w;
    }
#pragma unroll
    for (int d = 1; d < 64; d <<= 1) {
      a0 += __shfl_xor(a0, d); a1 += __shfl_xor(a1, d);
      a2 += __shfl_xor(a2, d); a3 += __shfl_xor(a3, d);
    }
    if (l == 0) {
      float bb = bfq[n] + bfg[n];
      gbias[n] = a0 + bb; gbias[1024 + n] = a1 + bb;
      gbias[2048 + n] = a2 + bb; gbias[3072 + n] = a3 + bb;
    }
  }
}

// ---------------- flash attention: aug-MFMA scores, dbuf K/V, counted-vmcnt barriers ----------------
template<int WP>
__global__ __launch_bounds__(512, 4)
void attn_flash(const u16* __restrict__ Qlin, const u16* __restrict__ Kf, const u16* __restrict__ Vf,
                const float* __restrict__ Pbuf, const float* __restrict__ IZbuf,
                u16* __restrict__ xbuf, float* __restrict__ Mbuf, float* __restrict__ iLbuf,
                u16* __restrict__ Pall, float* __restrict__ mch) {
  __shared__ u16 sm16[28672];   // buf i at i*10240: K 6144 + V 4096; ps at 20480 (8KB) -> 57344 B

  const int tid = threadIdx.x;
  const int l = tid & 63, w = tid >> 6;
  const int g = l >> 4, c = l & 15;
  const int bid = blockIdx.x;
  const int bh = (bid & 7) + ((bid >> 6) << 3);
  const int qc = (bid >> 3) & 7;
  const int b = bh >> 4, h = bh & 15;
  const int q0w = qc * 128 + w * 16;

  char* ps_ = (char*)(sm16 + 20480) + w * 2048;

  const u16* KfH = Kf + (size_t)bh * 98304;
  const u16* VfH = Vf + (size_t)bh * 65536;

  const u16* qrow = Qlin + (size_t)(b * 1024 + q0w + c) * 1024 + h * 64 + g * 8;
  short8 af0 = *(const short8*)qrow;
  short8 af1 = *(const short8*)(qrow + 32);
  short8 af2 = (short8){0, 0, 0, 0, 0, 0, 0, 0};
  if (g == 0) {
    float Pc = Pbuf[(size_t)bh * 1024 + q0w + c] - 512.0f;
    float Ic = IZbuf[(size_t)bh * 1024 + q0w + c];
    af2[0] = (short)f2bf(-Ic);
    af2[1] = (short)f2bf(2.0f * Pc * Ic);
    af2[2] = (short)f2bf(-Pc * Pc * Ic);
    af2[3] = (short)f2bf(1.0f);
  }

  float m[4], lsum[4];
  f32x4 xacc[4];
#pragma unroll
  for (int r = 0; r < 4; ++r) { m[r] = -3.0e38f; lsum[r] = 0.f; }
#pragma unroll
  for (int dt = 0; dt < 4; ++dt) xacc[dt] = (f32x4){0.f, 0.f, 0.f, 0.f};

  // per-stage VMEM issue: waves 0-3 -> 3 gl_lds, waves 4-7 -> 2 gl_lds
  auto stage = [&](int jn, u16* nb) {
    gl_lds16(KfH + (size_t)jn * 6144 + tid * 8, nb + tid * 8);
    if (tid < 256) {
      gl_lds16(KfH + (size_t)jn * 6144 + (512 + tid) * 8, nb + (512 + tid) * 8);
      int v = tid + 256;
      gl_lds16(VfH + ((size_t)((v >> 7) * 32 + jn * 2) * 512) + (v & 127) * 8, nb + 6144 + v * 8);
    } else {
      int v = tid - 256;
      gl_lds16(VfH + ((size_t)((v >> 7) * 32 + jn * 2) * 512) + (v & 127) * 8, nb + 6144 + v * 8);
    }
  };

  stage(0, sm16);
  __syncthreads();

  for (int jc = 0; jc < 16; ++jc) {
    const int bi = jc & 1;
    u16* Ksb = sm16 + bi * 10240;
    u16* Vsb = Ksb + 6144;
    if (jc < 15) stage(jc + 1, sm16 + (bi ^ 1) * 10240);

    // ---- QK^T + G + mask via 3 MFMAs (log2-space scores directly) ----
    f32x4 sc[4];
    float cm[4] = {-3.0e38f, -3.0e38f, -3.0e38f, -3.0e38f};
    __builtin_amdgcn_s_setprio(1);
#pragma unroll
    for (int t = 0; t < 4; ++t) {
      short8 b0 = *(const short8*)(Ksb + (t * 3 + 0) * 512 + l * 8);
      short8 b1 = *(const short8*)(Ksb + (t * 3 + 1) * 512 + l * 8);
      short8 b2 = *(const short8*)(Ksb + (t * 3 + 2) * 512 + l * 8);
      f32x4 z = (f32x4){0.f, 0.f, 0.f, 0.f};
      z = __builtin_amdgcn_mfma_f32_16x16x32_bf16(af0, b0, z, 0, 0, 0);
      z = __builtin_amdgcn_mfma_f32_16x16x32_bf16(af1, b1, z, 0, 0, 0);
      z = __builtin_amdgcn_mfma_f32_16x16x32_bf16(af2, b2, z, 0, 0, 0);
      sc[t] = z;
#pragma unroll
      for (int r = 0; r < 4; ++r) cm[r] = fmaxf(cm[r], z[r]);
    }
    __builtin_amdgcn_s_setprio(0);
#pragma unroll
    for (int d = 1; d < 16; d <<= 1)
#pragma unroll
      for (int r = 0; r < 4; ++r) cm[r] = fmaxf(cm[r], __shfl_xor(cm[r], d));
    float scale[4], ps[4];
#pragma unroll
    for (int r = 0; r < 4; ++r) {
      float nm = fmaxf(m[r], cm[r]);
      scale[r] = fexp2(m[r] - nm);
      m[r] = nm;
      ps[r] = 0.f;
    }
#pragma unroll
    for (int t = 0; t < 4; ++t) {
#pragma unroll
      for (int r = 0; r < 4; ++r) {
        float p = fexp2(sc[t][r] - m[r]);
        ps[r] += p;
        int row = g * 4 + r;
        int byte = (row * 128 + (t * 16 + c) * 2) ^ ((row & 7) << 4);
        *(u16*)(ps_ + byte) = f2bf(p);
      }
    }
#pragma unroll
    for (int r = 0; r < 4; ++r) {
      lsum[r] = lsum[r] * scale[r] + ps[r];
#pragma unroll
      for (int dt = 0; dt < 4; ++dt) xacc[dt][r] *= scale[r];
    }
    if (WP && c == 0) {
      f32x4 mv;
      mv.x = m[0]; mv.y = m[1]; mv.z = m[2]; mv.w = m[3];
      *(f32x4*)(mch + ((size_t)bh * 16 + jc) * 1024 + q0w + g * 4) = mv;
    }
    if (WP) {
#pragma unroll
      for (int k2 = 0; k2 < 2; ++k2) {
        int i = k2 * 512 + l * 8;
        int row = i >> 6, col = i & 63;
        int byte = (row * 128 + col * 2) ^ ((row & 7) << 4);
        short8 v = *(const short8*)(ps_ + byte);
        *(short8*)(Pall + (((size_t)bh * 16 + jc) * 1024 + q0w + row) * 64 + col) = v;
      }
    }
    // ---- PV ----
    short8 pa[2];
#pragma unroll
    for (int ks = 0; ks < 2; ++ks) {
      int abyte = (c * 128 + (ks * 32 + g * 8) * 2) ^ ((c & 7) << 4);
      pa[ks] = *(const short8*)(ps_ + abyte);
    }
    __builtin_amdgcn_s_setprio(1);
#pragma unroll
    for (int dt = 0; dt < 4; ++dt) {
#pragma unroll
      for (int ks = 0; ks < 2; ++ks) {
        short8 vb = *(const short8*)(Vsb + (dt * 2 + ks) * 512 + l * 8);
        xacc[dt] = __builtin_amdgcn_mfma_f32_16x16x32_bf16(pa[ks], vb, xacc[dt], 0, 0, 0);
      }
    }
    __builtin_amdgcn_s_setprio(0);
    // ---- counted wait: retire stage(jc+1) loads; leave this chunk's 3 stores in flight ----
    if (jc < 15) {
      if (WP) asm volatile("s_waitcnt vmcnt(3)" ::: "memory");
      else    asm volatile("s_waitcnt vmcnt(0)" ::: "memory");
    }
    __builtin_amdgcn_sched_barrier(0);
    __builtin_amdgcn_s_barrier();
    __builtin_amdgcn_sched_barrier(0);
  }

  // ---- finalize ----
#pragma unroll
  for (int d = 1; d < 16; d <<= 1)
#pragma unroll
    for (int r = 0; r < 4; ++r) lsum[r] += __shfl_xor(lsum[r], d);
  float iLr[4];
#pragma unroll
  for (int r = 0; r < 4; ++r) iLr[r] = 1.0f / lsum[r];
  if (c == 0) {
#pragma unroll
    for (int r = 0; r < 4; ++r) {
      size_t o = (size_t)bh * 1024 + q0w + g * 4 + r;
      Mbuf[o] = m[r];
      iLbuf[o] = iLr[r];
    }
  }
  // ---- x epilogue ----
  float* xs = (float*)sm16 + w * 1024;
#pragma unroll
  for (int dt = 0; dt < 4; ++dt)
#pragma unroll
    for (int r = 0; r < 4; ++r)
      xs[(g * 4 + r) * 64 + dt * 16 + c] = xacc[dt][r] * iLr[r];
#pragma unroll
  for (int k2 = 0; k2 < 4; ++k2) {
    int i = k2 * 256 + l * 4;
    int row = i >> 6, d0 = i & 63;
    f32x4 xv = *(const f32x4*)(xs + i);
    short4v o;
    o[0] = (short)f2bf(xv.x); o[1] = (short)f2bf(xv.y);
    o[2] = (short)f2bf(xv.z); o[3] = (short)f2bf(xv.w);
    *(short4v*)(xbuf + (size_t)(b * 1024 + q0w + row) * 1024 + h * 64 + d0) = o;
  }
}

// ---------------- merged epilogue: blocks [0,256) = W_o GEMM (f32 out); rest = meansum ----------------
__global__ __launch_bounds__(256, 3)
void epilogue_k(const u16* __restrict__ A, const u16* __restrict__ Bw,
                const float* __restrict__ bias, float* __restrict__ out0,
                const u16* __restrict__ Pall, const float* __restrict__ iLbuf,
                const float* __restrict__ Mbuf, const float* __restrict__ mchb,
                float* __restrict__ out2, int usePall) {
  __shared__ u16 As[128 * 64];
  __shared__ u16 Bs[128 * 64];
  const int bid = blockIdx.x;
  const int tid = threadIdx.x;
  if (bid >= 256) {
    if (!usePall) return;
    int bq = (bid - 256) * 2 + (tid >> 7);
    int b = bq >> 10, q = bq & 1023;
    int j = (tid & 127) * 8;
    int jc = j >> 6, jin = j & 63;
    float acc[8] = {0, 0, 0, 0, 0, 0, 0, 0};
    for (int h = 0; h < 16; ++h) {
      int bh = b * 16 + h;
      float M = Mbuf[(size_t)bh * 1024 + q];
      float iLh = iLbuf[(size_t)bh * 1024 + q];
      float mc = mchb[((size_t)bh * 16 + jc) * 1024 + q];
      float f = fexp2(mc - M) * iLh;
      short8 p = *(const short8*)(Pall + (((size_t)bh * 16 + jc) * 1024 + q) * 64 + jin);
#pragma unroll
      for (int i = 0; i < 8; ++i) acc[i] = fmaf(bf2f((u16)p[i]), f, acc[i]);
    }
    float* dst = out2 + (size_t)bq * 1024 + j;
#pragma unroll
    for (int i = 0; i < 8; ++i) dst[i] = acc[i] * 0.0625f;
    return;
  }
  // ---- GEMM path (128x128) ----
  const int l = tid & 63, w = tid >> 6;
  const int m0 = (bid & 31) * 128, n0 = (bid >> 5) * 128;
  const int wrow = (w & 1) * 64, wcol = (w >> 1) * 64;
  const int g = l >> 4, c = l & 15;

  GEMM_CORE(A, Bw)

#pragma unroll
  for (int n = 0; n < 4; ++n) {
    int col = n0 + wcol + n * 16 + c;
    float bv = bias[col];
#pragma unroll
    for (int m = 0; m < 4; ++m) {
#pragma unroll
      for (int r = 0; r < 4; ++r) {
        int rowg = m0 + wrow + m * 16 + g * 4 + r;
        out0[(size_t)rowg * 1024 + col] = acc[m][n][r] + bv;
      }
    }
  }
}

// ---------------- fallback mean: recompute QK^T from K fragments (exp2-space, K pre-scaled) ----------------
__global__ __launch_bounds__(512, 4)
void attn_mean(const u16* __restrict__ Qlin, const u16* __restrict__ Kf,
               const float* __restrict__ Pbuf, const float* __restrict__ IZbuf,
               const float* __restrict__ Mbuf, const float* __restrict__ iLbuf,
               const int* __restrict__ mask,
               float* __restrict__ out2) {
  const int tid = threadIdx.x;
  const int l = tid & 63, w = tid >> 6;
  const int g = l >> 4, c = l & 15;
  int chunk = (blockIdx.x % 8) * 64 + blockIdx.x / 8;
  const int b = chunk >> 7;
  const int qt = (chunk & 127) >> 1;
  const int jh = chunk & 1;
  const int q0 = qt * 16;
  const int jbase = jh * 512 + w * 64;

  float mb[4];
#pragma unroll
  for (int t = 0; t < 4; ++t)
    mb[t] = (mask[b * 1024 + jbase + t * 16 + c] == 0) ? -1.4e15f : 0.0f;

  f32x4 macc[4];
#pragma unroll
  for (int t = 0; t < 4; ++t) macc[t] = (f32x4){0.f, 0.f, 0.f, 0.f};

  for (int h = 0; h < 16; ++h) {
    const u16* qrow = Qlin + (size_t)(b * 1024 + q0 + c) * 1024 + h * 64 + g * 8;
    short8 af0 = *(const short8*)qrow;
    short8 af1 = *(const short8*)(qrow + 32);
    const u16* kb2 = Kf + ((size_t)((b * 16 + h) * 64 + jh * 32 + w * 4) * 3) * 512 + l * 8;
    float Pq[4], IZq[4], Mq[4], iLq[4];
#pragma unroll
    for (int r = 0; r < 4; ++r) {
      size_t o = (size_t)(b * 16 + h) * 1024 + q0 + g * 4 + r;
      Pq[r] = Pbuf[o]; IZq[r] = IZbuf[o]; Mq[r] = Mbuf[o]; iLq[r] = iLbuf[o] * 0.0625f;
    }
#pragma unroll
    for (int t = 0; t < 4; ++t) {
      short8 bf0 = *(const short8*)(kb2 + (t * 3 + 0) * 512);
      short8 bf1 = *(const short8*)(kb2 + (t * 3 + 1) * 512);
      f32x4 z = (f32x4){0.f, 0.f, 0.f, 0.f};
      z = __builtin_amdgcn_mfma_f32_16x16x32_bf16(af0, bf0, z, 0, 0, 0);
      z = __builtin_amdgcn_mfma_f32_16x16x32_bf16(af1, bf1, z, 0, 0, 0);
      float jf = (float)(jbase + t * 16 + c);
#pragma unroll
      for (int r = 0; r < 4; ++r) {
        float diff = jf - Pq[r];
        float s = z[r] + mb[t] - diff * diff * IZq[r];
        macc[t][r] += fexp2(s - Mq[r]) * iLq[r];
      }
    }
  }
#pragma unroll
  for (int t = 0; t < 4; ++t) {
#pragma unroll
    for (int r = 0; r < 4; ++r)
      out2[(size_t)(b * 1024 + q0 + g * 4 + r) * 1024 + jbase + t * 16 + c] = macc[t][r];
  }
}

// ---------------- host ----------------
extern "C" void kernel_launch(void* const* d_in, const int* in_sizes, int n_in,
                              void* d_out, int out_size, void* d_ws, size_t ws_size,
                              hipStream_t stream) {
  const float* q   = (const float*)d_in[0];
  const float* k   = (const float*)d_in[1];
  const float* v   = (const float*)d_in[2];
  const int*   msk = (const int*)d_in[3];
  const float* Wk  = (const float*)d_in[4];  const float* bk  = (const float*)d_in[5];
  const float* Wv  = (const float*)d_in[6];  const float* bv  = (const float*)d_in[7];
  const float* Wq  = (const float*)d_in[8];  const float* bq  = (const float*)d_in[9];
  const float* Wo  = (const float*)d_in[10]; const float* bo  = (const float*)d_in[11];
  const float* Wfq = (const float*)d_in[12]; const float* bfq = (const float*)d_in[13];
  const float* Wfg = (const float*)d_in[14]; const float* bfg = (const float*)d_in[15];
  const float* up  = (const float*)d_in[16]; const float* uz  = (const float*)d_in[17];

  const size_t MB = 1u << 20;
  char* base = (char*)d_ws;
  char* p = base;
  auto take = [&](size_t n) { char* r = p; p += (n + 255) & ~(size_t)255; return r; };
  // Long-lived zone (live through attention):
  u16* Kf   = (u16*)take(12 * MB);
  u16* Ql   = (u16*)take(8 * MB);
  u16* Vf   = (u16*)take(8 * MB);
  u16* xb   = (u16*)take(8 * MB);
  u16* wob  = (u16*)take(2 * MB);
  float* Pb    = (float*)take((size_t)65536 * 4);
  float* IZb   = (float*)take((size_t)65536 * 4);
  float* Mb    = (float*)take((size_t)65536 * 4);
  float* iLb   = (float*)take((size_t)65536 * 4);
  float* mch   = (float*)take((size_t)64 * 16 * 1024 * 4);   // 4MB
  float* gpart = (float*)take((size_t)64 * 4 * 1024 * 4);    // 1MB
  float* glo   = (float*)take(4096 * 4);
  float* gbias = (float*)take(4096 * 4);
  // Dead-by-attention pool (aliased by Pall):
  size_t pool_off = (size_t)(p - base);
  u16* qb   = (u16*)take(8 * MB);
  u16* kb   = (u16*)take(8 * MB);
  u16* vb   = (u16*)take(8 * MB);
  u16* wkb  = (u16*)take(2 * MB);
  u16* wvb  = (u16*)take(2 * MB);
  u16* wqb  = (u16*)take(2 * MB);
  u16* wfqb = (u16*)take(2 * MB);
  u16* Pall = (u16*)(base + pool_off);
  int usePall = (ws_size >= pool_off + (size_t)128 * MB) ? 1 : 0;

  float* out0 = (float*)d_out;
  float* out2 = out0 + (size_t)4 * 1024 * 1024;

  cvt_all<<<8960, 256, 0, stream>>>(q, k, v, Wk, Wv, Wq, Wfq, Wo,
                                    qb, kb, vb, wkb, wvb, wqb, wfqb, wob, msk, Kf);
  dim3 gg3(32, 8, 3);
  proj_qkv<<<gg3, 256, 0, stream>>>(qb, kb, vb, wqb, wkb, wvb, bq, bk, bv, Ql, Kf, Vf);
  dim3 gg(32, 8);
  glo_part_k<<<256, 128, 0, stream>>>(Ql, gpart);
  glo_reduce<<<32, 128, 0, stream>>>(gpart, glo);
  gbias_k<<<64, 256, 0, stream>>>(glo, Wfg, bfq, bfg, gbias);
  gemm_tanh_pz<<<gg, 256, 0, stream>>>(Ql, wfqb, gbias, up, uz, Pb, IZb);
  if (usePall) {
    attn_flash<1><<<512, 512, 0, stream>>>(Ql, Kf, Vf, Pb, IZb, xb, Mb, iLb, Pall, mch);
    epilogue_k<<<2304, 256, 0, stream>>>(xb, wob, bo, out0, Pall, iLb, Mb, mch, out2, 1);
  } else {
    attn_flash<0><<<512, 512, 0, stream>>>(Ql, Kf, Vf, Pb, IZb, xb, Mb, iLb, Pall, mch);
    attn_mean<<<512, 512, 0, stream>>>(Ql, Kf, Pb, IZb, Mb, iLb, msk, out2);
    epilogue_k<<<256, 256, 0, stream>>>(xb, wob, bo, out0, Pall, iLb, Mb, mch, out2, 0);
  }
}